// Round 16
// baseline (125.841 us; speedup 1.0000x reference)
//
#include <hip/hip_runtime.h>
#include <cmath>

// L=1024, N=2, E=1024, H=16, d=64, B*H=32 heads, chunk C=64, NC=16 chunks
// qh/kh: [b=32][l=1024][d=64] bf16 ; vt: [b=32][e=64][l=1024] bf16
// St/Spt: [b][c][e=64][d=64] ; zc: [b][c][64] f32
// attn rows m = l*2 + nb, cols h*64+e

#define EPS 1e-6f

typedef short bf16x8 __attribute__((ext_vector_type(8)));
typedef float f32x4 __attribute__((ext_vector_type(4)));

__device__ __forceinline__ float b2f(ushort u) {
    union { unsigned u32; float f; } x; x.u32 = ((unsigned)u) << 16; return x.f;
}
__device__ __forceinline__ ushort f2b(float f) {
    union { float f; unsigned u; } x; x.f = f;
    unsigned r = (x.u + 0x7fffu + ((x.u >> 16) & 1u)) >> 16;
    return (ushort)r;
}
__device__ __forceinline__ void gload16(const void* g, void* l) {
    __builtin_amdgcn_global_load_lds(
        (__attribute__((address_space(1))) void*)(uintptr_t)g,
        (__attribute__((address_space(3))) void*)l,
        16, 0, 0);
}

// ---------------------------------------------------------------------------
// bf16 MFMA GEMM mainloop v9 (round-12 measured-best): tile 128x128, BK=32,
// 4 waves (quadrants); NB=4 x 16KB = 64KB LDS; depth-2 counted-vmcnt:
//   iter t: stage(t+2) -> vmcnt(8) -> s_barrier -> sched_barrier -> ds_read
//   buf t&3 -> 16 MFMA. Tails vmcnt(4)/vmcnt(0).
// Race-safe at NB=4 (round-5/12 spacing; NB=2 counted variant failed round 7).
// Swizzle: 4 16B-slots/row, key (row>>1)&3, both sides (conflicts = 0).
// ---------------------------------------------------------------------------
template<int KSTEPS>
__device__ __forceinline__ void gemm_mainloop9(const ushort* __restrict__ A,
                                               const ushort* __restrict__ B,
                                               int brow, int bcol, int kbeg,
                                               ushort* Sh, f32x4 acc[4][4]) {
    const int K = 1024;
    const int BUFE = 8192;    // elems per buffer: 128*32 (A) + 128*32 (B)
    int tid = threadIdx.x;
    int w = tid >> 6, lane = tid & 63;
    int fr = lane & 15, hi = lane >> 4;
    int wr = w >> 1, wc = w & 1;

    const ushort* gsrc[4];
    int ldst[4];
    #pragma unroll
    for (int i = 0; i < 4; i++) {
        int s = (w * 4 + i) * 64 + lane;
        const ushort* base; int r, c;
        if (s < 512) { r = s >> 2; c = s & 3; base = A + (size_t)(brow + r) * K; }
        else { int s2 = s - 512; r = s2 >> 2; c = s2 & 3; base = B + (size_t)(bcol + r) * K; }
        gsrc[i] = base + kbeg + ((c ^ ((r >> 1) & 3)) * 8);
        ldst[i] = (w * 4 + i) * 512;
    }

    int ea[4], eb[4];
    #pragma unroll
    for (int m = 0; m < 4; m++) {
        int ra = wr * 64 + m * 16 + fr;
        ea[m] = ra * 32 + ((hi ^ ((ra >> 1) & 3)) * 8);
    }
    #pragma unroll
    for (int n = 0; n < 4; n++) {
        int rb = wc * 64 + n * 16 + fr;
        eb[n] = 4096 + rb * 32 + ((hi ^ ((rb >> 1) & 3)) * 8);
    }

    #pragma unroll
    for (int m = 0; m < 4; m++)
        #pragma unroll
        for (int n = 0; n < 4; n++)
            acc[m][n] = (f32x4){0.f, 0.f, 0.f, 0.f};

    // prologue: stage steps 0,1 into buffers 0,1
    #pragma unroll
    for (int p = 0; p < 2; p++)
        #pragma unroll
        for (int i = 0; i < 4; i++)
            gload16(gsrc[i] + p * 32, Sh + p * BUFE + ldst[i]);

    for (int t = 0; t < KSTEPS; ++t) {
        if (t + 2 < KSTEPS) {
            ushort* Sn = Sh + ((t + 2) & 3) * BUFE;
            #pragma unroll
            for (int i = 0; i < 4; i++) gload16(gsrc[i] + (t + 2) * 32, Sn + ldst[i]);
            asm volatile("s_waitcnt vmcnt(8)" ::: "memory");
        } else if (t + 1 < KSTEPS) {
            asm volatile("s_waitcnt vmcnt(4)" ::: "memory");
        } else {
            asm volatile("s_waitcnt vmcnt(0)" ::: "memory");
        }
        __builtin_amdgcn_s_barrier();          // all waves' stage(t) landed
        __builtin_amdgcn_sched_barrier(0);     // no ds_read hoisted above
        const ushort* Bc = Sh + (t & 3) * BUFE;
        bf16x8 af[4], bf[4];
        #pragma unroll
        for (int m = 0; m < 4; m++) af[m] = *(const bf16x8*)&Bc[ea[m]];
        #pragma unroll
        for (int n = 0; n < 4; n++) bf[n] = *(const bf16x8*)&Bc[eb[n]];
        #pragma unroll
        for (int m = 0; m < 4; m++)
            #pragma unroll
            for (int n = 0; n < 4; n++)
                acc[m][n] = __builtin_amdgcn_mfma_f32_16x16x32_bf16(af[m], bf[n], acc[m][n], 0, 0, 0);
    }
}

// proj GEMMs, XCD-swizzled 1D grid (384 = 8 XCD x 48):
// z=0 q(phi)->qh, z=1 k(phi)->kh, z=2 v->vt (transposed head layout)
__global__ __launch_bounds__(256, 2) void gemm_proj(
    const ushort* __restrict__ Aq, const ushort* __restrict__ Ak, const ushort* __restrict__ Av,
    const ushort* __restrict__ Bq, const ushort* __restrict__ Bk, const ushort* __restrict__ Bv,
    const float* __restrict__ bq, const float* __restrict__ bk, const float* __restrict__ bv,
    ushort* __restrict__ oq, ushort* __restrict__ ok, ushort* __restrict__ ov) {
    __shared__ ushort Sh[4 * 8192];
    int bid = blockIdx.x;
    int swz = (bid & 7) * 48 + (bid >> 3);   // per-XCD chunk for L2 locality
    int z = swz >> 7;                        // 128 tiles per GEMM
    int rem = swz & 127;
    int brow = (rem >> 3) * 128, bcol = (rem & 7) * 128;
    const ushort* A = (z == 0) ? Aq : (z == 1) ? Ak : Av;
    const ushort* B = (z == 0) ? Bq : (z == 1) ? Bk : Bv;
    const float* bias = (z == 0) ? bq : (z == 1) ? bk : bv;
    f32x4 acc[4][4];
    gemm_mainloop9<32>(A, B, brow, bcol, 0, Sh, acc);
    int tid = threadIdx.x, w = tid >> 6, lane = tid & 63;
    int fr = lane & 15, hi = lane >> 4;
    int wr = w >> 1, wc = w & 1;
    #pragma unroll
    for (int m = 0; m < 4; m++)
        #pragma unroll
        for (int n = 0; n < 4; n++)
            #pragma unroll
            for (int r = 0; r < 4; r++) {
                int grow = brow + wr * 64 + m * 16 + hi * 4 + r;
                int gcol = bcol + wc * 64 + n * 16 + fr;
                float v = acc[m][n][r] + bias[gcol];
                int l = grow >> 1, nb2 = grow & 1, h = gcol >> 6, dd = gcol & 63;
                if (z == 2) {
                    ov[(size_t)((nb2 * 16 + h) * 64 + dd) * 1024 + l] = f2b(v);
                } else {
                    v = (v > 0.f) ? v + 1.f : __expf(v);
                    ushort* out = (z == 0) ? oq : ok;
                    out[(size_t)((nb2 * 16 + h) * 1024 + l) * 64 + dd] = f2b(v);
                }
            }
}

// out GEMM, global split-K=2, grid 256 (8 x 32). Last-finisher per tile does
// the cross-K reduction + bias + final store (removes the reduce_out kernel).
// Deterministic: partials are exact f32; acc0+p1 == acc1+p0 bitwise.
// cnt[] zeroed by cast_all each call; finisher self-cleans for graph replays.
__global__ __launch_bounds__(256, 2) void gemm_outk(const ushort* __restrict__ A,
                                                    const ushort* __restrict__ B,
                                                    float* __restrict__ pbuf,
                                                    int* __restrict__ cnt,
                                                    const float* __restrict__ bias,
                                                    float* __restrict__ out) {
    __shared__ ushort Sh[4 * 8192];
    __shared__ int oldc;
    int bid = blockIdx.x;
    int swz = (bid & 7) * 32 + (bid >> 3);
    int z = swz >> 7;
    int rem = swz & 127;
    int brow = (rem >> 3) * 128, bcol = (rem & 7) * 128;
    f32x4 acc[4][4];
    gemm_mainloop9<16>(A, B, brow, bcol, z * 512, Sh, acc);
    int tid = threadIdx.x, w = tid >> 6, lane = tid & 63;
    int fr = lane & 15, hi = lane >> 4;
    int wr = w >> 1, wc = w & 1;
    float* pp = pbuf + (size_t)z * 2097152;
    #pragma unroll
    for (int m = 0; m < 4; m++)
        #pragma unroll
        for (int n = 0; n < 4; n++)
            #pragma unroll
            for (int r = 0; r < 4; r++) {
                int grow = brow + wr * 64 + m * 16 + hi * 4 + r;
                int gcol = bcol + wc * 64 + n * 16 + fr;
                pp[(size_t)grow * 1024 + gcol] = acc[m][n][r];
            }
    __threadfence();                 // release: partial stores visible device-wide
    __syncthreads();                 // all threads fenced
    if (tid == 0) oldc = atomicAdd(&cnt[rem], 1);
    __syncthreads();
    if (oldc == 1) {                 // second finisher: other partial is ready
        __threadfence();             // acquire: invalidate stale cache lines
        const float* po = pbuf + (size_t)(1 - z) * 2097152;
        #pragma unroll
        for (int m = 0; m < 4; m++)
            #pragma unroll
            for (int n = 0; n < 4; n++)
                #pragma unroll
                for (int r = 0; r < 4; r++) {
                    int grow = brow + wr * 64 + m * 16 + hi * 4 + r;
                    int gcol = bcol + wc * 64 + n * 16 + fr;
                    out[(size_t)grow * 1024 + gcol] =
                        acc[m][n][r] + po[(size_t)grow * 1024 + gcol] + bias[gcol];
                }
        if (tid == 0) cnt[rem] = 0;  // self-clean for next graph replay
    }
}

// ---------------------------------------------------------------------------
// merged f32 -> bf16 cast: z 0..2 -> q,k,v (2M elems); z 3..6 -> Wq,Wk,Wv,Wo (1M)
// also zeroes the split-K tile counters (block 0 of z=0).
// ---------------------------------------------------------------------------
__global__ __launch_bounds__(256) void cast_all(
    const float* __restrict__ i0, const float* __restrict__ i1, const float* __restrict__ i2,
    const float* __restrict__ i3, const float* __restrict__ i4, const float* __restrict__ i5,
    const float* __restrict__ i6,
    ushort* __restrict__ o0, ushort* __restrict__ o1, ushort* __restrict__ o2,
    ushort* __restrict__ o3, ushort* __restrict__ o4, ushort* __restrict__ o5,
    ushort* __restrict__ o6, int* __restrict__ cnt) {
    int z = blockIdx.z;
    if (z == 0 && blockIdx.x == 0 && threadIdx.x < 128) cnt[threadIdx.x] = 0;
    const float* in = (z == 0) ? i0 : (z == 1) ? i1 : (z == 2) ? i2 :
                      (z == 3) ? i3 : (z == 4) ? i4 : (z == 5) ? i5 : i6;
    ushort* out = (z == 0) ? o0 : (z == 1) ? o1 : (z == 2) ? o2 :
                  (z == 3) ? o3 : (z == 4) ? o4 : (z == 5) ? o5 : o6;
    int n4 = (z < 3) ? 524288 : 262144;
    int i = blockIdx.x * 256 + threadIdx.x;
    if (i < n4) {
        float4 f = ((const float4*)in)[i];
        ushort4 o; o.x = f2b(f.x); o.y = f2b(f.y); o.z = f2b(f.z); o.w = f2b(f.w);
        ((ushort4*)out)[i] = o;
    }
}

// ---------------------------------------------------------------------------
// Per-(head, chunk) KV sums, transposed out: St[b][c][e][d] = sum_s v[s][e]*k[s][d]
// zc[b][c][d] = sum_s k[s][d]
// ---------------------------------------------------------------------------
__global__ __launch_bounds__(256) void chunk_sums(const ushort* __restrict__ kh,
                                                  const ushort* __restrict__ vt,
                                                  float* __restrict__ St,
                                                  float* __restrict__ zc) {
    int c = blockIdx.x, b = blockIdx.y, tid = threadIdx.x;
    __shared__ float Kl[64][64];
    __shared__ float Vl[64][65];
    const ushort* Kg = kh + (size_t)(b * 1024 + c * 64) * 64;
    for (int i = tid; i < 1024; i += 256) {
        ushort4 k4 = ((const ushort4*)Kg)[i];
        ((float4*)Kl)[i] = make_float4(b2f(k4.x), b2f(k4.y), b2f(k4.z), b2f(k4.w));
        int e = i >> 4, s4 = (i & 15) << 2;
        ushort4 v4 = *(const ushort4*)&vt[(size_t)(b * 64 + e) * 1024 + c * 64 + s4];
        Vl[e][s4 + 0] = b2f(v4.x); Vl[e][s4 + 1] = b2f(v4.y);
        Vl[e][s4 + 2] = b2f(v4.z); Vl[e][s4 + 3] = b2f(v4.w);
    }
    __syncthreads();
    int e = tid & 63, d0 = (tid >> 6) * 16;
    float s[16] = {};
    for (int ss = 0; ss < 64; ss++) {
        float ve = Vl[e][ss];
        #pragma unroll
        for (int i = 0; i < 16; i++) s[i] += Kl[ss][d0 + i] * ve;
    }
    float* So = St + (size_t)(b * 16 + c) * 4096 + e * 64 + d0;
    #pragma unroll
    for (int k = 0; k < 4; k++)
        *(float4*)&So[k * 4] = make_float4(s[4*k], s[4*k+1], s[4*k+2], s[4*k+3]);
    if (tid < 64) {
        float z = 0.f;
        for (int ss = 0; ss < 64; ss++) z += Kl[ss][tid];
        zc[(size_t)(b * 16 + c) * 64 + tid] = z;
    }
}

// exclusive prefix over chunks: St (f32) -> Spt (bf16), zc in-place.
// grid (32 heads, 4 e-slices) = 128 blocks.
__global__ __launch_bounds__(256) void prefix_chunks(const float* __restrict__ St,
                                                     ushort* __restrict__ Spt,
                                                     float* __restrict__ zc) {
    int b = blockIdx.x, by = blockIdx.y, tid = threadIdx.x;
    int e = by * 16 + (tid >> 4);
    int d0 = (tid & 15) * 4;
    size_t base = (size_t)b * 65536 + (size_t)e * 64 + d0;
    float run[4] = {};
    for (int c = 0; c < 16; c++) {
        float4 v = *(const float4*)&St[base + (size_t)c * 4096];
        ushort4 o;
        o.x = f2b(run[0]); o.y = f2b(run[1]); o.z = f2b(run[2]); o.w = f2b(run[3]);
        *(ushort4*)&Spt[base + (size_t)c * 4096] = o;
        run[0] += v.x; run[1] += v.y; run[2] += v.z; run[3] += v.w;
    }
    if (by == 0 && tid < 64) {
        float rz = 0.f;
        for (int c = 0; c < 16; c++) {
            size_t idx = ((size_t)b * 16 + c) * 64 + tid;
            float t = zc[idx];
            zc[idx] = rz;
            rz += t;
        }
    }
}

// ---------------------------------------------------------------------------
// MFMA attention per (b, c): P = phiQ phiK^T (masked), num = phiQ S_prev + P V,
// den = phiQ z_prev + rowsum(P); attn = num/den (bf16)
// All LDS tiles 64x64 bf16, XOR-swizzled (key = row&7 on 16B slots).
// ---------------------------------------------------------------------------
__global__ __launch_bounds__(256) void attn_chunk(const ushort* __restrict__ qh,
                                                  const ushort* __restrict__ kh,
                                                  const ushort* __restrict__ vt,
                                                  const ushort* __restrict__ Spt,
                                                  const float* __restrict__ zc,
                                                  ushort* __restrict__ attn) {
    int c = blockIdx.x, b = blockIdx.y, tid = threadIdx.x;
    int w = tid >> 6, lane = tid & 63;
    int fr = lane & 15, hi = lane >> 4;
    __shared__ ushort Q[4096], Kt[4096], VT[4096], SP[4096], P[4096];
    __shared__ float den[64];

    {
        const ushort* bases[4];
        bases[0] = qh + (size_t)(b * 1024 + c * 64) * 64;
        bases[1] = kh + (size_t)(b * 1024 + c * 64) * 64;
        bases[2] = vt;
        bases[3] = Spt + (size_t)(b * 16 + c) * 4096;
        ushort* dsts[4] = {Q, Kt, VT, SP};
        #pragma unroll
        for (int tl = 0; tl < 4; tl++) {
            #pragma unroll
            for (int j = 0; j < 2; j++) {
                int i = w * 64 + lane + 256 * j;
                int row = i >> 3, sl = i & 7;
                int col = (sl ^ (row & 7)) * 8;
                const ushort* src;
                if (tl == 2) src = vt + (size_t)(b * 64 + row) * 1024 + c * 64 + col;
                else         src = bases[tl] + (size_t)row * 64 + col;
                gload16(src, dsts[tl] + w * 512 + 2048 * j);
            }
        }
    }
    __syncthreads();

    // phase A: P = QK^T
    int frow = w * 16 + fr;
    int fkey = fr & 7;
    bf16x8 aq[2];
    #pragma unroll
    for (int kk = 0; kk < 2; kk++)
        aq[kk] = *(const bf16x8*)&Q[frow * 64 + ((kk * 4 + hi) ^ fkey) * 8];
    f32x4 pc[4];
    #pragma unroll
    for (int n = 0; n < 4; n++) {
        pc[n] = (f32x4){0.f, 0.f, 0.f, 0.f};
        #pragma unroll
        for (int kk = 0; kk < 2; kk++) {
            bf16x8 bk_ = *(const bf16x8*)&Kt[(n * 16 + fr) * 64 + ((kk * 4 + hi) ^ fkey) * 8];
            pc[n] = __builtin_amdgcn_mfma_f32_16x16x32_bf16(aq[kk], bk_, pc[n], 0, 0, 0);
        }
    }
    float denp[4] = {0.f, 0.f, 0.f, 0.f};
    #pragma unroll
    for (int n = 0; n < 4; n++)
        #pragma unroll
        for (int r = 0; r < 4; r++) {
            int t = w * 16 + hi * 4 + r;
            int s = n * 16 + fr;
            float v = (s <= t) ? pc[n][r] : 0.f;
            denp[r] += v;
            P[t * 64 + (((s >> 3) ^ (t & 7)) * 8) + (s & 7)] = f2b(v);
        }
    #pragma unroll
    for (int r = 0; r < 4; r++) {
        denp[r] += __shfl_xor(denp[r], 1);
        denp[r] += __shfl_xor(denp[r], 2);
        denp[r] += __shfl_xor(denp[r], 4);
        denp[r] += __shfl_xor(denp[r], 8);
    }
    if (fr == 0) {
        #pragma unroll
        for (int r = 0; r < 4; r++) den[w * 16 + hi * 4 + r] = denp[r];
    }
    __syncthreads();

    if (tid < 64) {
        int t = tid;
        const float* zg = zc + (size_t)(b * 16 + c) * 64;
        float a = 0.f;
        for (int d = 0; d < 64; d++)
            a += b2f(Q[t * 64 + (((d >> 3) ^ (t & 7)) * 8) + (d & 7)]) * zg[d];
        den[t] += a;
    }

    // phase B: num = Q @ SP-rows + P @ VT-rows
    bf16x8 ap[2];
    #pragma unroll
    for (int kk = 0; kk < 2; kk++)
        ap[kk] = *(const bf16x8*)&P[frow * 64 + ((kk * 4 + hi) ^ fkey) * 8];
    f32x4 nacc[4];
    #pragma unroll
    for (int n = 0; n < 4; n++) {
        nacc[n] = (f32x4){0.f, 0.f, 0.f, 0.f};
        #pragma unroll
        for (int kk = 0; kk < 2; kk++) {
            bf16x8 bs = *(const bf16x8*)&SP[(n * 16 + fr) * 64 + ((kk * 4 + hi) ^ fkey) * 8];
            nacc[n] = __builtin_amdgcn_mfma_f32_16x16x32_bf16(aq[kk], bs, nacc[n], 0, 0, 0);
        }
        #pragma unroll
        for (int kk = 0; kk < 2; kk++) {
            bf16x8 bv = *(const bf16x8*)&VT[(n * 16 + fr) * 64 + ((kk * 4 + hi) ^ fkey) * 8];
            nacc[n] = __builtin_amdgcn_mfma_f32_16x16x32_bf16(ap[kk], bv, nacc[n], 0, 0, 0);
        }
    }
    __syncthreads();

    int nb = b >> 4, h = b & 15;
    #pragma unroll
    for (int n = 0; n < 4; n++)
        #pragma unroll
        for (int r = 0; r < 4; r++) {
            int t = w * 16 + hi * 4 + r;
            int e = n * 16 + fr;
            int l = c * 64 + t;
            float val = nacc[n][r] / (den[t] + EPS);
            attn[(size_t)(l * 2 + nb) * 1024 + h * 64 + e] = f2b(val);
        }
}

// ---------------------------------------------------------------------------
extern "C" void kernel_launch(void* const* d_in, const int* in_sizes, int n_in,
                              void* d_out, int out_size, void* d_ws, size_t ws_size,
                              hipStream_t stream) {
    const float* query = (const float*)d_in[0];
    const float* key_  = (const float*)d_in[1];
    const float* value = (const float*)d_in[2];
    const float* Wq = (const float*)d_in[3];
    const float* bq = (const float*)d_in[4];
    const float* Wk = (const float*)d_in[5];
    const float* bk = (const float*)d_in[6];
    const float* Wv = (const float*)d_in[7];
    const float* bv = (const float*)d_in[8];
    const float* Wo = (const float*)d_in[9];
    const float* bo = (const float*)d_in[10];

    // workspace layout
    ushort* qbuf = (ushort*)d_ws;          // 2M u16
    ushort* kbuf = qbuf + 2097152;
    ushort* vbuf = kbuf + 2097152;
    ushort* wqb  = vbuf + 2097152;         // 1M u16 x4
    ushort* wkb  = wqb + 1048576;
    ushort* wvb  = wkb + 1048576;
    ushort* wob  = wvb + 1048576;
    ushort* qh   = wob + 1048576;          // 2M u16 x3
    ushort* kh   = qh + 2097152;
    ushort* vt   = kh + 2097152;
    float*  St   = (float*)(vt + 2097152); // 2M f32
    ushort* Spt  = (ushort*)(St + 2097152);// 2M u16
    float*  zc   = (float*)(Spt + 2097152);// 32K f32
    float*  pbuf = zc + 32768;             // 2 x 2M f32 (split-K partials)
    int*    cnt  = (int*)(pbuf + 4194304); // 128 tile counters
    ushort* attn = qbuf;                   // qbuf dead after proj

    cast_all<<<dim3(2048, 1, 7), 256, 0, stream>>>(query, key_, value, Wq, Wk, Wv, Wo,
                                                   qbuf, kbuf, vbuf, wqb, wkb, wvb, wob, cnt);

    gemm_proj<<<384, 256, 0, stream>>>(qbuf, kbuf, vbuf, wqb, wkb, wvb,
                                       bq, bk, bv, qh, kh, vt);

    chunk_sums<<<dim3(16, 32), 256, 0, stream>>>(kh, vt, St, zc);
    prefix_chunks<<<dim3(32, 4), 256, 0, stream>>>(St, Spt, zc);
    attn_chunk<<<dim3(16, 32), 256, 0, stream>>>(qh, kh, vt, Spt, zc, attn);

    gemm_outk<<<256, 256, 0, stream>>>(attn, wob, pbuf, cnt, bo, (float*)d_out);
}

// Round 17
// 81.868 us; speedup vs baseline: 1.5371x; 1.5371x over previous
//
#include <hip/hip_runtime.h>
#include <cmath>

// L=1024, N=2, E=1024, H=16, d=64, B*H=32 heads, chunk C=64, NC=16 chunks
// qh/kh: [b=32][l=1024][d=64] bf16 ; vt: [b=32][e=64][l=1024] bf16
// St/Spt: [b][c][e=64][d=64] ; zc: [b][c][64] f32
// attn rows m = l*2 + nb, cols h*64+e

#define EPS 1e-6f

typedef short bf16x8 __attribute__((ext_vector_type(8)));
typedef float f32x4 __attribute__((ext_vector_type(4)));

__device__ __forceinline__ float b2f(ushort u) {
    union { unsigned u32; float f; } x; x.u32 = ((unsigned)u) << 16; return x.f;
}
__device__ __forceinline__ ushort f2b(float f) {
    union { float f; unsigned u; } x; x.f = f;
    unsigned r = (x.u + 0x7fffu + ((x.u >> 16) & 1u)) >> 16;
    return (ushort)r;
}
__device__ __forceinline__ void gload16(const void* g, void* l) {
    __builtin_amdgcn_global_load_lds(
        (__attribute__((address_space(1))) void*)(uintptr_t)g,
        (__attribute__((address_space(3))) void*)l,
        16, 0, 0);
}

// ---------------------------------------------------------------------------
// bf16 MFMA GEMM mainloop v9 (measured-best, rounds 12/15): tile 128x128,
// BK=32, 4 waves (quadrants); NB=4 x 16KB = 64KB LDS; depth-2 counted-vmcnt:
//   iter t: stage(t+2) -> vmcnt(8) -> s_barrier -> sched_barrier -> ds_read
//   buf t&3 -> 16 MFMA. Tails vmcnt(4)/vmcnt(0).
// Race-safe at NB=4 (round-5/12 spacing; NB=2 counted variant failed round 7).
// Swizzle: 4 16B-slots/row, key (row>>1)&3, both sides (conflicts = 0).
// ---------------------------------------------------------------------------
template<int KSTEPS>
__device__ __forceinline__ void gemm_mainloop9(const ushort* __restrict__ A,
                                               const ushort* __restrict__ B,
                                               int brow, int bcol, int kbeg,
                                               ushort* Sh, f32x4 acc[4][4]) {
    const int K = 1024;
    const int BUFE = 8192;    // elems per buffer: 128*32 (A) + 128*32 (B)
    int tid = threadIdx.x;
    int w = tid >> 6, lane = tid & 63;
    int fr = lane & 15, hi = lane >> 4;
    int wr = w >> 1, wc = w & 1;

    const ushort* gsrc[4];
    int ldst[4];
    #pragma unroll
    for (int i = 0; i < 4; i++) {
        int s = (w * 4 + i) * 64 + lane;
        const ushort* base; int r, c;
        if (s < 512) { r = s >> 2; c = s & 3; base = A + (size_t)(brow + r) * K; }
        else { int s2 = s - 512; r = s2 >> 2; c = s2 & 3; base = B + (size_t)(bcol + r) * K; }
        gsrc[i] = base + kbeg + ((c ^ ((r >> 1) & 3)) * 8);
        ldst[i] = (w * 4 + i) * 512;
    }

    int ea[4], eb[4];
    #pragma unroll
    for (int m = 0; m < 4; m++) {
        int ra = wr * 64 + m * 16 + fr;
        ea[m] = ra * 32 + ((hi ^ ((ra >> 1) & 3)) * 8);
    }
    #pragma unroll
    for (int n = 0; n < 4; n++) {
        int rb = wc * 64 + n * 16 + fr;
        eb[n] = 4096 + rb * 32 + ((hi ^ ((rb >> 1) & 3)) * 8);
    }

    #pragma unroll
    for (int m = 0; m < 4; m++)
        #pragma unroll
        for (int n = 0; n < 4; n++)
            acc[m][n] = (f32x4){0.f, 0.f, 0.f, 0.f};

    // prologue: stage steps 0,1 into buffers 0,1
    #pragma unroll
    for (int p = 0; p < 2; p++)
        #pragma unroll
        for (int i = 0; i < 4; i++)
            gload16(gsrc[i] + p * 32, Sh + p * BUFE + ldst[i]);

    for (int t = 0; t < KSTEPS; ++t) {
        if (t + 2 < KSTEPS) {
            ushort* Sn = Sh + ((t + 2) & 3) * BUFE;
            #pragma unroll
            for (int i = 0; i < 4; i++) gload16(gsrc[i] + (t + 2) * 32, Sn + ldst[i]);
            asm volatile("s_waitcnt vmcnt(8)" ::: "memory");
        } else if (t + 1 < KSTEPS) {
            asm volatile("s_waitcnt vmcnt(4)" ::: "memory");
        } else {
            asm volatile("s_waitcnt vmcnt(0)" ::: "memory");
        }
        __builtin_amdgcn_s_barrier();          // all waves' stage(t) landed
        __builtin_amdgcn_sched_barrier(0);     // no ds_read hoisted above
        const ushort* Bc = Sh + (t & 3) * BUFE;
        bf16x8 af[4], bf[4];
        #pragma unroll
        for (int m = 0; m < 4; m++) af[m] = *(const bf16x8*)&Bc[ea[m]];
        #pragma unroll
        for (int n = 0; n < 4; n++) bf[n] = *(const bf16x8*)&Bc[eb[n]];
        #pragma unroll
        for (int m = 0; m < 4; m++)
            #pragma unroll
            for (int n = 0; n < 4; n++)
                acc[m][n] = __builtin_amdgcn_mfma_f32_16x16x32_bf16(af[m], bf[n], acc[m][n], 0, 0, 0);
    }
}

// proj GEMMs, XCD-swizzled 1D grid (384 = 8 XCD x 48):
// z=0 q(phi)->qh, z=1 k(phi)->kh, z=2 v->vt (transposed head layout)
__global__ __launch_bounds__(256, 2) void gemm_proj(
    const ushort* __restrict__ Aq, const ushort* __restrict__ Ak, const ushort* __restrict__ Av,
    const ushort* __restrict__ Bq, const ushort* __restrict__ Bk, const ushort* __restrict__ Bv,
    const float* __restrict__ bq, const float* __restrict__ bk, const float* __restrict__ bv,
    ushort* __restrict__ oq, ushort* __restrict__ ok, ushort* __restrict__ ov) {
    __shared__ ushort Sh[4 * 8192];
    int bid = blockIdx.x;
    int swz = (bid & 7) * 48 + (bid >> 3);   // per-XCD chunk for L2 locality
    int z = swz >> 7;                        // 128 tiles per GEMM
    int rem = swz & 127;
    int brow = (rem >> 3) * 128, bcol = (rem & 7) * 128;
    const ushort* A = (z == 0) ? Aq : (z == 1) ? Ak : Av;
    const ushort* B = (z == 0) ? Bq : (z == 1) ? Bk : Bv;
    const float* bias = (z == 0) ? bq : (z == 1) ? bk : bv;
    f32x4 acc[4][4];
    gemm_mainloop9<32>(A, B, brow, bcol, 0, Sh, acc);
    int tid = threadIdx.x, w = tid >> 6, lane = tid & 63;
    int fr = lane & 15, hi = lane >> 4;
    int wr = w >> 1, wc = w & 1;
    #pragma unroll
    for (int m = 0; m < 4; m++)
        #pragma unroll
        for (int n = 0; n < 4; n++)
            #pragma unroll
            for (int r = 0; r < 4; r++) {
                int grow = brow + wr * 64 + m * 16 + hi * 4 + r;
                int gcol = bcol + wc * 64 + n * 16 + fr;
                float v = acc[m][n][r] + bias[gcol];
                int l = grow >> 1, nb2 = grow & 1, h = gcol >> 6, dd = gcol & 63;
                if (z == 2) {
                    ov[(size_t)((nb2 * 16 + h) * 64 + dd) * 1024 + l] = f2b(v);
                } else {
                    v = (v > 0.f) ? v + 1.f : __expf(v);
                    ushort* out = (z == 0) ? oq : ok;
                    out[(size_t)((nb2 * 16 + h) * 1024 + l) * 64 + dd] = f2b(v);
                }
            }
}

// out GEMM, global split-K=2, XCD-swizzled 1D grid (256 = 8 x 32 = 1 block/CU)
__global__ __launch_bounds__(256, 2) void gemm_outk(const ushort* __restrict__ A,
                                                    const ushort* __restrict__ B,
                                                    float* __restrict__ pbuf) {
    __shared__ ushort Sh[4 * 8192];
    int bid = blockIdx.x;
    int swz = (bid & 7) * 32 + (bid >> 3);
    int z = swz >> 7;
    int rem = swz & 127;
    int brow = (rem >> 3) * 128, bcol = (rem & 7) * 128;
    f32x4 acc[4][4];
    gemm_mainloop9<16>(A, B, brow, bcol, z * 512, Sh, acc);
    int tid = threadIdx.x, w = tid >> 6, lane = tid & 63;
    int fr = lane & 15, hi = lane >> 4;
    int wr = w >> 1, wc = w & 1;
    float* out = pbuf + (size_t)z * 2097152;
    #pragma unroll
    for (int m = 0; m < 4; m++)
        #pragma unroll
        for (int n = 0; n < 4; n++)
            #pragma unroll
            for (int r = 0; r < 4; r++) {
                int grow = brow + wr * 64 + m * 16 + hi * 4 + r;
                int gcol = bcol + wc * 64 + n * 16 + fr;
                out[(size_t)grow * 1024 + gcol] = acc[m][n][r];
            }
}

__global__ __launch_bounds__(256) void reduce_out(const float* __restrict__ p,
                                                  const float* __restrict__ bias,
                                                  float* __restrict__ out) {
    int i = blockIdx.x * 256 + threadIdx.x;      // over 524288 float4s
    float4 a = ((const float4*)p)[i];
    float4 b = ((const float4*)(p + 2097152))[i];
    float4 bb = ((const float4*)bias)[i & 255];
    float4 o;
    o.x = a.x + b.x + bb.x;
    o.y = a.y + b.y + bb.y;
    o.z = a.z + b.z + bb.z;
    o.w = a.w + b.w + bb.w;
    ((float4*)out)[i] = o;
}

// ---------------------------------------------------------------------------
// merged f32 -> bf16 cast: z 0..2 -> q,k,v (2M elems); z 3..6 -> Wq,Wk,Wv,Wo (1M)
// ---------------------------------------------------------------------------
__global__ __launch_bounds__(256) void cast_all(
    const float* __restrict__ i0, const float* __restrict__ i1, const float* __restrict__ i2,
    const float* __restrict__ i3, const float* __restrict__ i4, const float* __restrict__ i5,
    const float* __restrict__ i6,
    ushort* __restrict__ o0, ushort* __restrict__ o1, ushort* __restrict__ o2,
    ushort* __restrict__ o3, ushort* __restrict__ o4, ushort* __restrict__ o5,
    ushort* __restrict__ o6) {
    int z = blockIdx.z;
    const float* in = (z == 0) ? i0 : (z == 1) ? i1 : (z == 2) ? i2 :
                      (z == 3) ? i3 : (z == 4) ? i4 : (z == 5) ? i5 : i6;
    ushort* out = (z == 0) ? o0 : (z == 1) ? o1 : (z == 2) ? o2 :
                  (z == 3) ? o3 : (z == 4) ? o4 : (z == 5) ? o5 : o6;
    int n4 = (z < 3) ? 524288 : 262144;
    int i = blockIdx.x * 256 + threadIdx.x;
    if (i < n4) {
        float4 f = ((const float4*)in)[i];
        ushort4 o; o.x = f2b(f.x); o.y = f2b(f.y); o.z = f2b(f.z); o.w = f2b(f.w);
        ((ushort4*)out)[i] = o;
    }
}

// ---------------------------------------------------------------------------
// Per-(head, chunk) KV sums, transposed out: St[b][c][e][d] = sum_s v[s][e]*k[s][d]
// zc[b][c][d] = sum_s k[s][d]
// ---------------------------------------------------------------------------
__global__ __launch_bounds__(256) void chunk_sums(const ushort* __restrict__ kh,
                                                  const ushort* __restrict__ vt,
                                                  float* __restrict__ St,
                                                  float* __restrict__ zc) {
    int c = blockIdx.x, b = blockIdx.y, tid = threadIdx.x;
    __shared__ float Kl[64][64];
    __shared__ float Vl[64][65];
    const ushort* Kg = kh + (size_t)(b * 1024 + c * 64) * 64;
    for (int i = tid; i < 1024; i += 256) {
        ushort4 k4 = ((const ushort4*)Kg)[i];
        ((float4*)Kl)[i] = make_float4(b2f(k4.x), b2f(k4.y), b2f(k4.z), b2f(k4.w));
        int e = i >> 4, s4 = (i & 15) << 2;
        ushort4 v4 = *(const ushort4*)&vt[(size_t)(b * 64 + e) * 1024 + c * 64 + s4];
        Vl[e][s4 + 0] = b2f(v4.x); Vl[e][s4 + 1] = b2f(v4.y);
        Vl[e][s4 + 2] = b2f(v4.z); Vl[e][s4 + 3] = b2f(v4.w);
    }
    __syncthreads();
    int e = tid & 63, d0 = (tid >> 6) * 16;
    float s[16] = {};
    for (int ss = 0; ss < 64; ss++) {
        float ve = Vl[e][ss];
        #pragma unroll
        for (int i = 0; i < 16; i++) s[i] += Kl[ss][d0 + i] * ve;
    }
    float* So = St + (size_t)(b * 16 + c) * 4096 + e * 64 + d0;
    #pragma unroll
    for (int k = 0; k < 4; k++)
        *(float4*)&So[k * 4] = make_float4(s[4*k], s[4*k+1], s[4*k+2], s[4*k+3]);
    if (tid < 64) {
        float z = 0.f;
        for (int ss = 0; ss < 64; ss++) z += Kl[ss][tid];
        zc[(size_t)(b * 16 + c) * 64 + tid] = z;
    }
}

// exclusive prefix over chunks: St (f32) -> Spt (bf16), zc in-place.
// grid (32 heads, 4 e-slices) = 128 blocks.
__global__ __launch_bounds__(256) void prefix_chunks(const float* __restrict__ St,
                                                     ushort* __restrict__ Spt,
                                                     float* __restrict__ zc) {
    int b = blockIdx.x, by = blockIdx.y, tid = threadIdx.x;
    int e = by * 16 + (tid >> 4);
    int d0 = (tid & 15) * 4;
    size_t base = (size_t)b * 65536 + (size_t)e * 64 + d0;
    float run[4] = {};
    for (int c = 0; c < 16; c++) {
        float4 v = *(const float4*)&St[base + (size_t)c * 4096];
        ushort4 o;
        o.x = f2b(run[0]); o.y = f2b(run[1]); o.z = f2b(run[2]); o.w = f2b(run[3]);
        *(ushort4*)&Spt[base + (size_t)c * 4096] = o;
        run[0] += v.x; run[1] += v.y; run[2] += v.z; run[3] += v.w;
    }
    if (by == 0 && tid < 64) {
        float rz = 0.f;
        for (int c = 0; c < 16; c++) {
            size_t idx = ((size_t)b * 16 + c) * 64 + tid;
            float t = zc[idx];
            zc[idx] = rz;
            rz += t;
        }
    }
}

// ---------------------------------------------------------------------------
// MFMA attention per (b, c): P = phiQ phiK^T (masked), num = phiQ S_prev + P V,
// den = phiQ z_prev + rowsum(P); attn = num/den (bf16)
// All LDS tiles 64x64 bf16, XOR-swizzled (key = row&7 on 16B slots).
// ---------------------------------------------------------------------------
__global__ __launch_bounds__(256) void attn_chunk(const ushort* __restrict__ qh,
                                                  const ushort* __restrict__ kh,
                                                  const ushort* __restrict__ vt,
                                                  const ushort* __restrict__ Spt,
                                                  const float* __restrict__ zc,
                                                  ushort* __restrict__ attn) {
    int c = blockIdx.x, b = blockIdx.y, tid = threadIdx.x;
    int w = tid >> 6, lane = tid & 63;
    int fr = lane & 15, hi = lane >> 4;
    __shared__ ushort Q[4096], Kt[4096], VT[4096], SP[4096], P[4096];
    __shared__ float den[64];

    {
        const ushort* bases[4];
        bases[0] = qh + (size_t)(b * 1024 + c * 64) * 64;
        bases[1] = kh + (size_t)(b * 1024 + c * 64) * 64;
        bases[2] = vt;
        bases[3] = Spt + (size_t)(b * 16 + c) * 4096;
        ushort* dsts[4] = {Q, Kt, VT, SP};
        #pragma unroll
        for (int tl = 0; tl < 4; tl++) {
            #pragma unroll
            for (int j = 0; j < 2; j++) {
                int i = w * 64 + lane + 256 * j;
                int row = i >> 3, sl = i & 7;
                int col = (sl ^ (row & 7)) * 8;
                const ushort* src;
                if (tl == 2) src = vt + (size_t)(b * 64 + row) * 1024 + c * 64 + col;
                else         src = bases[tl] + (size_t)row * 64 + col;
                gload16(src, dsts[tl] + w * 512 + 2048 * j);
            }
        }
    }
    __syncthreads();

    // phase A: P = QK^T
    int frow = w * 16 + fr;
    int fkey = fr & 7;
    bf16x8 aq[2];
    #pragma unroll
    for (int kk = 0; kk < 2; kk++)
        aq[kk] = *(const bf16x8*)&Q[frow * 64 + ((kk * 4 + hi) ^ fkey) * 8];
    f32x4 pc[4];
    #pragma unroll
    for (int n = 0; n < 4; n++) {
        pc[n] = (f32x4){0.f, 0.f, 0.f, 0.f};
        #pragma unroll
        for (int kk = 0; kk < 2; kk++) {
            bf16x8 bk_ = *(const bf16x8*)&Kt[(n * 16 + fr) * 64 + ((kk * 4 + hi) ^ fkey) * 8];
            pc[n] = __builtin_amdgcn_mfma_f32_16x16x32_bf16(aq[kk], bk_, pc[n], 0, 0, 0);
        }
    }
    float denp[4] = {0.f, 0.f, 0.f, 0.f};
    #pragma unroll
    for (int n = 0; n < 4; n++)
        #pragma unroll
        for (int r = 0; r < 4; r++) {
            int t = w * 16 + hi * 4 + r;
            int s = n * 16 + fr;
            float v = (s <= t) ? pc[n][r] : 0.f;
            denp[r] += v;
            P[t * 64 + (((s >> 3) ^ (t & 7)) * 8) + (s & 7)] = f2b(v);
        }
    #pragma unroll
    for (int r = 0; r < 4; r++) {
        denp[r] += __shfl_xor(denp[r], 1);
        denp[r] += __shfl_xor(denp[r], 2);
        denp[r] += __shfl_xor(denp[r], 4);
        denp[r] += __shfl_xor(denp[r], 8);
    }
    if (fr == 0) {
        #pragma unroll
        for (int r = 0; r < 4; r++) den[w * 16 + hi * 4 + r] = denp[r];
    }
    __syncthreads();

    if (tid < 64) {
        int t = tid;
        const float* zg = zc + (size_t)(b * 16 + c) * 64;
        float a = 0.f;
        for (int d = 0; d < 64; d++)
            a += b2f(Q[t * 64 + (((d >> 3) ^ (t & 7)) * 8) + (d & 7)]) * zg[d];
        den[t] += a;
    }

    // phase B: num = Q @ SP-rows + P @ VT-rows
    bf16x8 ap[2];
    #pragma unroll
    for (int kk = 0; kk < 2; kk++)
        ap[kk] = *(const bf16x8*)&P[frow * 64 + ((kk * 4 + hi) ^ fkey) * 8];
    f32x4 nacc[4];
    #pragma unroll
    for (int n = 0; n < 4; n++) {
        nacc[n] = (f32x4){0.f, 0.f, 0.f, 0.f};
        #pragma unroll
        for (int kk = 0; kk < 2; kk++) {
            bf16x8 bs = *(const bf16x8*)&SP[(n * 16 + fr) * 64 + ((kk * 4 + hi) ^ fkey) * 8];
            nacc[n] = __builtin_amdgcn_mfma_f32_16x16x32_bf16(aq[kk], bs, nacc[n], 0, 0, 0);
        }
        #pragma unroll
        for (int kk = 0; kk < 2; kk++) {
            bf16x8 bv = *(const bf16x8*)&VT[(n * 16 + fr) * 64 + ((kk * 4 + hi) ^ fkey) * 8];
            nacc[n] = __builtin_amdgcn_mfma_f32_16x16x32_bf16(ap[kk], bv, nacc[n], 0, 0, 0);
        }
    }
    __syncthreads();

    int nb = b >> 4, h = b & 15;
    #pragma unroll
    for (int n = 0; n < 4; n++)
        #pragma unroll
        for (int r = 0; r < 4; r++) {
            int t = w * 16 + hi * 4 + r;
            int e = n * 16 + fr;
            int l = c * 64 + t;
            float val = nacc[n][r] / (den[t] + EPS);
            attn[(size_t)(l * 2 + nb) * 1024 + h * 64 + e] = f2b(val);
        }
}

// ---------------------------------------------------------------------------
extern "C" void kernel_launch(void* const* d_in, const int* in_sizes, int n_in,
                              void* d_out, int out_size, void* d_ws, size_t ws_size,
                              hipStream_t stream) {
    const float* query = (const float*)d_in[0];
    const float* key_  = (const float*)d_in[1];
    const float* value = (const float*)d_in[2];
    const float* Wq = (const float*)d_in[3];
    const float* bq = (const float*)d_in[4];
    const float* Wk = (const float*)d_in[5];
    const float* bk = (const float*)d_in[6];
    const float* Wv = (const float*)d_in[7];
    const float* bv = (const float*)d_in[8];
    const float* Wo = (const float*)d_in[9];
    const float* bo = (const float*)d_in[10];

    // workspace layout
    ushort* qbuf = (ushort*)d_ws;          // 2M u16
    ushort* kbuf = qbuf + 2097152;
    ushort* vbuf = kbuf + 2097152;
    ushort* wqb  = vbuf + 2097152;         // 1M u16 x4
    ushort* wkb  = wqb + 1048576;
    ushort* wvb  = wkb + 1048576;
    ushort* wob  = wvb + 1048576;
    ushort* qh   = wob + 1048576;          // 2M u16 x3
    ushort* kh   = qh + 2097152;
    ushort* vt   = kh + 2097152;
    float*  St   = (float*)(vt + 2097152); // 2M f32
    ushort* Spt  = (ushort*)(St + 2097152);// 2M u16
    float*  zc   = (float*)(Spt + 2097152);// 32K f32
    float*  pbuf = zc + 32768;             // 2 x 2M f32 (split-K partials)
    ushort* attn = qbuf;                   // qbuf dead after proj

    cast_all<<<dim3(2048, 1, 7), 256, 0, stream>>>(query, key_, value, Wq, Wk, Wv, Wo,
                                                   qbuf, kbuf, vbuf, wqb, wkb, wvb, wob);

    gemm_proj<<<384, 256, 0, stream>>>(qbuf, kbuf, vbuf, wqb, wkb, wvb,
                                       bq, bk, bv, qh, kh, vt);

    chunk_sums<<<dim3(16, 32), 256, 0, stream>>>(kh, vt, St, zc);
    prefix_chunks<<<dim3(32, 4), 256, 0, stream>>>(St, Spt, zc);
    attn_chunk<<<dim3(16, 32), 256, 0, stream>>>(qh, kh, vt, Spt, zc, attn);

    gemm_outk<<<256, 256, 0, stream>>>(attn, wob, pbuf);
    reduce_out<<<2048, 256, 0, stream>>>(pbuf, bo, (float*)d_out);
}

// Round 18
// 79.756 us; speedup vs baseline: 1.5778x; 1.0265x over previous
//
#include <hip/hip_runtime.h>
#include <cmath>

// L=1024, N=2, E=1024, H=16, d=64, B*H=32 heads, chunk C=64, NC=16 chunks
// qh/kh: [b=32][l=1024][d=64] bf16 ; vt: [b=32][e=64][l=1024] bf16
// St(bf16)/Spt(bf16): [b][c][e=64][d=64] ; zc: [b][c][64] f32
// attn rows m = l*2 + nb, cols h*64+e

#define EPS 1e-6f

typedef short bf16x8 __attribute__((ext_vector_type(8)));
typedef float f32x4 __attribute__((ext_vector_type(4)));

__device__ __forceinline__ float b2f(ushort u) {
    union { unsigned u32; float f; } x; x.u32 = ((unsigned)u) << 16; return x.f;
}
__device__ __forceinline__ ushort f2b(float f) {
    union { float f; unsigned u; } x; x.f = f;
    unsigned r = (x.u + 0x7fffu + ((x.u >> 16) & 1u)) >> 16;
    return (ushort)r;
}
__device__ __forceinline__ void gload16(const void* g, void* l) {
    __builtin_amdgcn_global_load_lds(
        (__attribute__((address_space(1))) void*)(uintptr_t)g,
        (__attribute__((address_space(3))) void*)l,
        16, 0, 0);
}

// ---------------------------------------------------------------------------
// bf16 MFMA GEMM mainloop v9 (measured-best, rounds 12/15/17): tile 128x128,
// BK=32, 4 waves (quadrants); NB=4 x 16KB = 64KB LDS; depth-2 counted-vmcnt:
//   iter t: stage(t+2) -> vmcnt(8) -> s_barrier -> sched_barrier -> ds_read
//   buf t&3 -> 16 MFMA. Tails vmcnt(4)/vmcnt(0).
// Race-safe at NB=4 (round-5/12 spacing; NB=2 counted variant failed round 7).
// Swizzle: 4 16B-slots/row, key (row>>1)&3, both sides (conflicts = 0).
// ---------------------------------------------------------------------------
template<int KSTEPS>
__device__ __forceinline__ void gemm_mainloop9(const ushort* __restrict__ A,
                                               const ushort* __restrict__ B,
                                               int brow, int bcol, int kbeg,
                                               ushort* Sh, f32x4 acc[4][4]) {
    const int K = 1024;
    const int BUFE = 8192;    // elems per buffer: 128*32 (A) + 128*32 (B)
    int tid = threadIdx.x;
    int w = tid >> 6, lane = tid & 63;
    int fr = lane & 15, hi = lane >> 4;
    int wr = w >> 1, wc = w & 1;

    const ushort* gsrc[4];
    int ldst[4];
    #pragma unroll
    for (int i = 0; i < 4; i++) {
        int s = (w * 4 + i) * 64 + lane;
        const ushort* base; int r, c;
        if (s < 512) { r = s >> 2; c = s & 3; base = A + (size_t)(brow + r) * K; }
        else { int s2 = s - 512; r = s2 >> 2; c = s2 & 3; base = B + (size_t)(bcol + r) * K; }
        gsrc[i] = base + kbeg + ((c ^ ((r >> 1) & 3)) * 8);
        ldst[i] = (w * 4 + i) * 512;
    }

    int ea[4], eb[4];
    #pragma unroll
    for (int m = 0; m < 4; m++) {
        int ra = wr * 64 + m * 16 + fr;
        ea[m] = ra * 32 + ((hi ^ ((ra >> 1) & 3)) * 8);
    }
    #pragma unroll
    for (int n = 0; n < 4; n++) {
        int rb = wc * 64 + n * 16 + fr;
        eb[n] = 4096 + rb * 32 + ((hi ^ ((rb >> 1) & 3)) * 8);
    }

    #pragma unroll
    for (int m = 0; m < 4; m++)
        #pragma unroll
        for (int n = 0; n < 4; n++)
            acc[m][n] = (f32x4){0.f, 0.f, 0.f, 0.f};

    // prologue: stage steps 0,1 into buffers 0,1
    #pragma unroll
    for (int p = 0; p < 2; p++)
        #pragma unroll
        for (int i = 0; i < 4; i++)
            gload16(gsrc[i] + p * 32, Sh + p * BUFE + ldst[i]);

    for (int t = 0; t < KSTEPS; ++t) {
        if (t + 2 < KSTEPS) {
            ushort* Sn = Sh + ((t + 2) & 3) * BUFE;
            #pragma unroll
            for (int i = 0; i < 4; i++) gload16(gsrc[i] + (t + 2) * 32, Sn + ldst[i]);
            asm volatile("s_waitcnt vmcnt(8)" ::: "memory");
        } else if (t + 1 < KSTEPS) {
            asm volatile("s_waitcnt vmcnt(4)" ::: "memory");
        } else {
            asm volatile("s_waitcnt vmcnt(0)" ::: "memory");
        }
        __builtin_amdgcn_s_barrier();          // all waves' stage(t) landed
        __builtin_amdgcn_sched_barrier(0);     // no ds_read hoisted above
        const ushort* Bc = Sh + (t & 3) * BUFE;
        bf16x8 af[4], bf[4];
        #pragma unroll
        for (int m = 0; m < 4; m++) af[m] = *(const bf16x8*)&Bc[ea[m]];
        #pragma unroll
        for (int n = 0; n < 4; n++) bf[n] = *(const bf16x8*)&Bc[eb[n]];
        #pragma unroll
        for (int m = 0; m < 4; m++)
            #pragma unroll
            for (int n = 0; n < 4; n++)
                acc[m][n] = __builtin_amdgcn_mfma_f32_16x16x32_bf16(af[m], bf[n], acc[m][n], 0, 0, 0);
    }
}

// proj GEMMs, XCD-swizzled 1D grid (384 = 8 XCD x 48):
// z=0 q(phi)->qh, z=1 k(phi)->kh, z=2 v->vt (transposed head layout)
__global__ __launch_bounds__(256, 2) void gemm_proj(
    const ushort* __restrict__ Aq, const ushort* __restrict__ Ak, const ushort* __restrict__ Av,
    const ushort* __restrict__ Bq, const ushort* __restrict__ Bk, const ushort* __restrict__ Bv,
    const float* __restrict__ bq, const float* __restrict__ bk, const float* __restrict__ bv,
    ushort* __restrict__ oq, ushort* __restrict__ ok, ushort* __restrict__ ov) {
    __shared__ ushort Sh[4 * 8192];
    int bid = blockIdx.x;
    int swz = (bid & 7) * 48 + (bid >> 3);   // per-XCD chunk for L2 locality
    int z = swz >> 7;                        // 128 tiles per GEMM
    int rem = swz & 127;
    int brow = (rem >> 3) * 128, bcol = (rem & 7) * 128;
    const ushort* A = (z == 0) ? Aq : (z == 1) ? Ak : Av;
    const ushort* B = (z == 0) ? Bq : (z == 1) ? Bk : Bv;
    const float* bias = (z == 0) ? bq : (z == 1) ? bk : bv;
    f32x4 acc[4][4];
    gemm_mainloop9<32>(A, B, brow, bcol, 0, Sh, acc);
    int tid = threadIdx.x, w = tid >> 6, lane = tid & 63;
    int fr = lane & 15, hi = lane >> 4;
    int wr = w >> 1, wc = w & 1;
    #pragma unroll
    for (int m = 0; m < 4; m++)
        #pragma unroll
        for (int n = 0; n < 4; n++)
            #pragma unroll
            for (int r = 0; r < 4; r++) {
                int grow = brow + wr * 64 + m * 16 + hi * 4 + r;
                int gcol = bcol + wc * 64 + n * 16 + fr;
                float v = acc[m][n][r] + bias[gcol];
                int l = grow >> 1, nb2 = grow & 1, h = gcol >> 6, dd = gcol & 63;
                if (z == 2) {
                    ov[(size_t)((nb2 * 16 + h) * 64 + dd) * 1024 + l] = f2b(v);
                } else {
                    v = (v > 0.f) ? v + 1.f : __expf(v);
                    ushort* out = (z == 0) ? oq : ok;
                    out[(size_t)((nb2 * 16 + h) * 1024 + l) * 64 + dd] = f2b(v);
                }
            }
}

// out GEMM, global split-K=2, XCD-swizzled 1D grid (256 = 8 x 32 = 1 block/CU)
// bf16 partials (precision measured safe in round 14).
__global__ __launch_bounds__(256, 2) void gemm_outk(const ushort* __restrict__ A,
                                                    const ushort* __restrict__ B,
                                                    ushort* __restrict__ pbuf) {
    __shared__ ushort Sh[4 * 8192];
    int bid = blockIdx.x;
    int swz = (bid & 7) * 32 + (bid >> 3);
    int z = swz >> 7;
    int rem = swz & 127;
    int brow = (rem >> 3) * 128, bcol = (rem & 7) * 128;
    f32x4 acc[4][4];
    gemm_mainloop9<16>(A, B, brow, bcol, z * 512, Sh, acc);
    int tid = threadIdx.x, w = tid >> 6, lane = tid & 63;
    int fr = lane & 15, hi = lane >> 4;
    int wr = w >> 1, wc = w & 1;
    ushort* pp = pbuf + (size_t)z * 2097152;
    #pragma unroll
    for (int m = 0; m < 4; m++)
        #pragma unroll
        for (int n = 0; n < 4; n++)
            #pragma unroll
            for (int r = 0; r < 4; r++) {
                int grow = brow + wr * 64 + m * 16 + hi * 4 + r;
                int gcol = bcol + wc * 64 + n * 16 + fr;
                pp[(size_t)grow * 1024 + gcol] = f2b(acc[m][n][r]);
            }
}

// reduce 2 bf16 partials + bias -> f32 out. grid 1024 x 256.
__global__ __launch_bounds__(256) void reduce_out(const ushort* __restrict__ pbuf,
                                                  const float* __restrict__ bias,
                                                  float* __restrict__ out) {
    int idx = blockIdx.x * 256 + threadIdx.x;
    int row = idx >> 7, c0 = (idx & 127) * 8;
    const ushort* p = pbuf + (size_t)row * 1024 + c0;
    bf16x8 a = *(const bf16x8*)p;
    bf16x8 b = *(const bf16x8*)(p + 2097152);
    float* o = out + (size_t)row * 1024 + c0;
    #pragma unroll
    for (int j = 0; j < 8; j++)
        o[j] = b2f((ushort)a[j]) + b2f((ushort)b[j]) + bias[c0 + j];
}

// ---------------------------------------------------------------------------
// merged f32 -> bf16 cast: z 0..2 -> q,k,v (2M elems); z 3..6 -> Wq,Wk,Wv,Wo (1M)
// ---------------------------------------------------------------------------
__global__ __launch_bounds__(256) void cast_all(
    const float* __restrict__ i0, const float* __restrict__ i1, const float* __restrict__ i2,
    const float* __restrict__ i3, const float* __restrict__ i4, const float* __restrict__ i5,
    const float* __restrict__ i6,
    ushort* __restrict__ o0, ushort* __restrict__ o1, ushort* __restrict__ o2,
    ushort* __restrict__ o3, ushort* __restrict__ o4, ushort* __restrict__ o5,
    ushort* __restrict__ o6) {
    int z = blockIdx.z;
    const float* in = (z == 0) ? i0 : (z == 1) ? i1 : (z == 2) ? i2 :
                      (z == 3) ? i3 : (z == 4) ? i4 : (z == 5) ? i5 : i6;
    ushort* out = (z == 0) ? o0 : (z == 1) ? o1 : (z == 2) ? o2 :
                  (z == 3) ? o3 : (z == 4) ? o4 : (z == 5) ? o5 : o6;
    int n4 = (z < 3) ? 524288 : 262144;
    int i = blockIdx.x * 256 + threadIdx.x;
    if (i < n4) {
        float4 f = ((const float4*)in)[i];
        ushort4 o; o.x = f2b(f.x); o.y = f2b(f.y); o.z = f2b(f.z); o.w = f2b(f.w);
        ((ushort4*)out)[i] = o;
    }
}

// ---------------------------------------------------------------------------
// Per-(head, chunk) KV sums, transposed out (bf16 storage, f32 accumulate):
// St[b][c][e][d] = sum_s v[s][e]*k[s][d] ; zc[b][c][d] = sum_s k[s][d]
// ---------------------------------------------------------------------------
__global__ __launch_bounds__(256) void chunk_sums(const ushort* __restrict__ kh,
                                                  const ushort* __restrict__ vt,
                                                  ushort* __restrict__ St,
                                                  float* __restrict__ zc) {
    int c = blockIdx.x, b = blockIdx.y, tid = threadIdx.x;
    __shared__ float Kl[64][64];
    __shared__ float Vl[64][65];
    const ushort* Kg = kh + (size_t)(b * 1024 + c * 64) * 64;
    for (int i = tid; i < 1024; i += 256) {
        ushort4 k4 = ((const ushort4*)Kg)[i];
        ((float4*)Kl)[i] = make_float4(b2f(k4.x), b2f(k4.y), b2f(k4.z), b2f(k4.w));
        int e = i >> 4, s4 = (i & 15) << 2;
        ushort4 v4 = *(const ushort4*)&vt[(size_t)(b * 64 + e) * 1024 + c * 64 + s4];
        Vl[e][s4 + 0] = b2f(v4.x); Vl[e][s4 + 1] = b2f(v4.y);
        Vl[e][s4 + 2] = b2f(v4.z); Vl[e][s4 + 3] = b2f(v4.w);
    }
    __syncthreads();
    int e = tid & 63, d0 = (tid >> 6) * 16;
    float s[16] = {};
    for (int ss = 0; ss < 64; ss++) {
        float ve = Vl[e][ss];
        #pragma unroll
        for (int i = 0; i < 16; i++) s[i] += Kl[ss][d0 + i] * ve;
    }
    ushort* So = St + (size_t)(b * 16 + c) * 4096 + e * 64 + d0;
    #pragma unroll
    for (int k = 0; k < 4; k++) {
        ushort4 o;
        o.x = f2b(s[4*k+0]); o.y = f2b(s[4*k+1]);
        o.z = f2b(s[4*k+2]); o.w = f2b(s[4*k+3]);
        *(ushort4*)&So[k * 4] = o;
    }
    if (tid < 64) {
        float z = 0.f;
        for (int ss = 0; ss < 64; ss++) z += Kl[ss][tid];
        zc[(size_t)(b * 16 + c) * 64 + tid] = z;
    }
}

// exclusive prefix over chunks: St (bf16) -> Spt (bf16, f32 running sum),
// zc in-place. grid (32 heads, 4 e-slices) = 128 blocks.
__global__ __launch_bounds__(256) void prefix_chunks(const ushort* __restrict__ St,
                                                     ushort* __restrict__ Spt,
                                                     float* __restrict__ zc) {
    int b = blockIdx.x, by = blockIdx.y, tid = threadIdx.x;
    int e = by * 16 + (tid >> 4);
    int d0 = (tid & 15) * 4;
    size_t base = (size_t)b * 65536 + (size_t)e * 64 + d0;
    float run[4] = {};
    for (int c = 0; c < 16; c++) {
        ushort4 v4 = *(const ushort4*)&St[base + (size_t)c * 4096];
        ushort4 o;
        o.x = f2b(run[0]); o.y = f2b(run[1]); o.z = f2b(run[2]); o.w = f2b(run[3]);
        *(ushort4*)&Spt[base + (size_t)c * 4096] = o;
        run[0] += b2f(v4.x); run[1] += b2f(v4.y);
        run[2] += b2f(v4.z); run[3] += b2f(v4.w);
    }
    if (by == 0 && tid < 64) {
        float rz = 0.f;
        for (int c = 0; c < 16; c++) {
            size_t idx = ((size_t)b * 16 + c) * 64 + tid;
            float t = zc[idx];
            zc[idx] = rz;
            rz += t;
        }
    }
}

// ---------------------------------------------------------------------------
// MFMA attention per (b, c): P = phiQ phiK^T (masked), num = phiQ S_prev + P V,
// den = phiQ z_prev + rowsum(P); attn = num/den (bf16)
// All LDS tiles 64x64 bf16, XOR-swizzled (key = row&7 on 16B slots).
// ---------------------------------------------------------------------------
__global__ __launch_bounds__(256) void attn_chunk(const ushort* __restrict__ qh,
                                                  const ushort* __restrict__ kh,
                                                  const ushort* __restrict__ vt,
                                                  const ushort* __restrict__ Spt,
                                                  const float* __restrict__ zc,
                                                  ushort* __restrict__ attn) {
    int c = blockIdx.x, b = blockIdx.y, tid = threadIdx.x;
    int w = tid >> 6, lane = tid & 63;
    int fr = lane & 15, hi = lane >> 4;
    __shared__ ushort Q[4096], Kt[4096], VT[4096], SP[4096], P[4096];
    __shared__ float den[64];

    {
        const ushort* bases[4];
        bases[0] = qh + (size_t)(b * 1024 + c * 64) * 64;
        bases[1] = kh + (size_t)(b * 1024 + c * 64) * 64;
        bases[2] = vt;
        bases[3] = Spt + (size_t)(b * 16 + c) * 4096;
        ushort* dsts[4] = {Q, Kt, VT, SP};
        #pragma unroll
        for (int tl = 0; tl < 4; tl++) {
            #pragma unroll
            for (int j = 0; j < 2; j++) {
                int i = w * 64 + lane + 256 * j;
                int row = i >> 3, sl = i & 7;
                int col = (sl ^ (row & 7)) * 8;
                const ushort* src;
                if (tl == 2) src = vt + (size_t)(b * 64 + row) * 1024 + c * 64 + col;
                else         src = bases[tl] + (size_t)row * 64 + col;
                gload16(src, dsts[tl] + w * 512 + 2048 * j);
            }
        }
    }
    __syncthreads();

    // phase A: P = QK^T
    int frow = w * 16 + fr;
    int fkey = fr & 7;
    bf16x8 aq[2];
    #pragma unroll
    for (int kk = 0; kk < 2; kk++)
        aq[kk] = *(const bf16x8*)&Q[frow * 64 + ((kk * 4 + hi) ^ fkey) * 8];
    f32x4 pc[4];
    #pragma unroll
    for (int n = 0; n < 4; n++) {
        pc[n] = (f32x4){0.f, 0.f, 0.f, 0.f};
        #pragma unroll
        for (int kk = 0; kk < 2; kk++) {
            bf16x8 bk_ = *(const bf16x8*)&Kt[(n * 16 + fr) * 64 + ((kk * 4 + hi) ^ fkey) * 8];
            pc[n] = __builtin_amdgcn_mfma_f32_16x16x32_bf16(aq[kk], bk_, pc[n], 0, 0, 0);
        }
    }
    float denp[4] = {0.f, 0.f, 0.f, 0.f};
    #pragma unroll
    for (int n = 0; n < 4; n++)
        #pragma unroll
        for (int r = 0; r < 4; r++) {
            int t = w * 16 + hi * 4 + r;
            int s = n * 16 + fr;
            float v = (s <= t) ? pc[n][r] : 0.f;
            denp[r] += v;
            P[t * 64 + (((s >> 3) ^ (t & 7)) * 8) + (s & 7)] = f2b(v);
        }
    #pragma unroll
    for (int r = 0; r < 4; r++) {
        denp[r] += __shfl_xor(denp[r], 1);
        denp[r] += __shfl_xor(denp[r], 2);
        denp[r] += __shfl_xor(denp[r], 4);
        denp[r] += __shfl_xor(denp[r], 8);
    }
    if (fr == 0) {
        #pragma unroll
        for (int r = 0; r < 4; r++) den[w * 16 + hi * 4 + r] = denp[r];
    }
    __syncthreads();

    if (tid < 64) {
        int t = tid;
        const float* zg = zc + (size_t)(b * 16 + c) * 64;
        float a = 0.f;
        for (int d = 0; d < 64; d++)
            a += b2f(Q[t * 64 + (((d >> 3) ^ (t & 7)) * 8) + (d & 7)]) * zg[d];
        den[t] += a;
    }

    // phase B: num = Q @ SP-rows + P @ VT-rows
    bf16x8 ap[2];
    #pragma unroll
    for (int kk = 0; kk < 2; kk++)
        ap[kk] = *(const bf16x8*)&P[frow * 64 + ((kk * 4 + hi) ^ fkey) * 8];
    f32x4 nacc[4];
    #pragma unroll
    for (int n = 0; n < 4; n++) {
        nacc[n] = (f32x4){0.f, 0.f, 0.f, 0.f};
        #pragma unroll
        for (int kk = 0; kk < 2; kk++) {
            bf16x8 bs = *(const bf16x8*)&SP[(n * 16 + fr) * 64 + ((kk * 4 + hi) ^ fkey) * 8];
            nacc[n] = __builtin_amdgcn_mfma_f32_16x16x32_bf16(aq[kk], bs, nacc[n], 0, 0, 0);
        }
        #pragma unroll
        for (int kk = 0; kk < 2; kk++) {
            bf16x8 bv = *(const bf16x8*)&VT[(n * 16 + fr) * 64 + ((kk * 4 + hi) ^ fkey) * 8];
            nacc[n] = __builtin_amdgcn_mfma_f32_16x16x32_bf16(ap[kk], bv, nacc[n], 0, 0, 0);
        }
    }
    __syncthreads();

    int nb = b >> 4, h = b & 15;
    #pragma unroll
    for (int n = 0; n < 4; n++)
        #pragma unroll
        for (int r = 0; r < 4; r++) {
            int t = w * 16 + hi * 4 + r;
            int e = n * 16 + fr;
            int l = c * 64 + t;
            float val = nacc[n][r] / (den[t] + EPS);
            attn[(size_t)(l * 2 + nb) * 1024 + h * 64 + e] = f2b(val);
        }
}

// ---------------------------------------------------------------------------
extern "C" void kernel_launch(void* const* d_in, const int* in_sizes, int n_in,
                              void* d_out, int out_size, void* d_ws, size_t ws_size,
                              hipStream_t stream) {
    const float* query = (const float*)d_in[0];
    const float* key_  = (const float*)d_in[1];
    const float* value = (const float*)d_in[2];
    const float* Wq = (const float*)d_in[3];
    const float* bq = (const float*)d_in[4];
    const float* Wk = (const float*)d_in[5];
    const float* bk = (const float*)d_in[6];
    const float* Wv = (const float*)d_in[7];
    const float* bv = (const float*)d_in[8];
    const float* Wo = (const float*)d_in[9];
    const float* bo = (const float*)d_in[10];

    // workspace layout (u16 units)
    ushort* qbuf = (ushort*)d_ws;          // 2M u16
    ushort* kbuf = qbuf + 2097152;
    ushort* vbuf = kbuf + 2097152;
    ushort* wqb  = vbuf + 2097152;         // 1M u16 x4
    ushort* wkb  = wqb + 1048576;
    ushort* wvb  = wkb + 1048576;
    ushort* wob  = wvb + 1048576;
    ushort* qh   = wob + 1048576;          // 2M u16 x3
    ushort* kh   = qh + 2097152;
    ushort* vt   = kh + 2097152;
    ushort* St   = vt + 2097152;           // 2M u16 (bf16 chunk sums)
    ushort* Spt  = St + 2097152;           // 2M u16 (bf16 exclusive prefix)
    float*  zc   = (float*)(Spt + 2097152);// 32K f32
    ushort* pbuf = (ushort*)(zc + 32768);  // 2 x 2M u16 (bf16 split-K partials)
    ushort* attn = qbuf;                   // qbuf dead after proj

    cast_all<<<dim3(2048, 1, 7), 256, 0, stream>>>(query, key_, value, Wq, Wk, Wv, Wo,
                                                   qbuf, kbuf, vbuf, wqb, wkb, wvb, wob);

    gemm_proj<<<384, 256, 0, stream>>>(qbuf, kbuf, vbuf, wqb, wkb, wvb,
                                       bq, bk, bv, qh, kh, vt);

    chunk_sums<<<dim3(16, 32), 256, 0, stream>>>(kh, vt, St, zc);
    prefix_chunks<<<dim3(32, 4), 256, 0, stream>>>(St, Spt, zc);
    attn_chunk<<<dim3(16, 32), 256, 0, stream>>>(qh, kh, vt, Spt, zc, attn);

    gemm_outk<<<256, 256, 0, stream>>>(attn, wob, pbuf);
    reduce_out<<<1024, 256, 0, stream>>>(pbuf, bo, (float*)d_out);
}